// Round 11
// baseline (313.980 us; speedup 1.0000x reference)
//
#include <hip/hip_runtime.h>
#include <hip/hip_fp16.h>
#include <math.h>
#include <stdint.h>

#define DEV __device__ __forceinline__

using f32x4 = __attribute__((ext_vector_type(4))) float;
using half8 = __attribute__((ext_vector_type(8))) _Float16;
typedef union { uint4 u; half8 h; } u4h8;

DEV float lrelu(float x){ return x > 0.f ? x : 0.01f*x; }
DEV float elu1(float x){ return x > 0.f ? x : __expf(x)-1.f; }

DEV int lower_bound_i(const int* __restrict__ a, int n, int key){
  int lo = 0, hi = n;
  while (lo < hi){ int mid = (lo+hi)>>1; if (a[mid] < key) lo = mid+1; else hi = mid; }
  return lo;
}

// ============ combined prep: all weight splits + zero CSR/scan state ============
DEV void wsplit(float v, unsigned short* __restrict__ H, unsigned short* __restrict__ L, size_t o){
  __half h = __float2half_rn(v);
  float lo = (v - __half2float(h)) * 1024.f;
  H[o] = __half_as_ushort(h);
  L[o] = __half_as_ushort(__float2half_rn(lo));
}

__global__ void wprep_all(const float* __restrict__ W1, const float* __restrict__ gW,
    const float* __restrict__ mW,
    unsigned short* __restrict__ w1h, unsigned short* __restrict__ w1l,
    unsigned short* __restrict__ gwh, unsigned short* __restrict__ gwl,
    unsigned short* __restrict__ mwh, unsigned short* __restrict__ mwl,
    int* __restrict__ deg, unsigned long long* __restrict__ bstat,
    int* __restrict__ bctr, int Nn, int nG, int nscan)
{
  int i = blockIdx.x*256 + threadIdx.x;
  if (i < Nn) deg[i] = 0;
  if (i < nscan) bstat[i] = 0ull;
  if (i == 0) *bctr = 0;
  if (i < 8192){                       // W1 [64][128] -> [128][64]
    int k = i >> 7, n = i & 127;
    wsplit(W1[i], w1h, w1l, (size_t)n*64 + k);
  }
  if (i < nG){                         // gW [NL][128][128] -> [NL][128][128]T
    int mat = i >> 14; int rem = i & 16383;
    int k = rem >> 7, n = rem & 127;
    wsplit(gW[i], gwh, gwl, (size_t)mat*16384 + (size_t)n*128 + k);
  }
  if (i < 16384){                      // mW
    int k = i >> 7, n = i & 127;
    wsplit(mW[i], mwh, mwl, (size_t)n*128 + k);
  }
}

// ============ lin1 GEMM: h = lrelu(x[M,64] @ W1 + b1) -> fp16 (x converted in-kernel) ============
__global__ __launch_bounds__(256, 3) void gemm_lin1(
    const float* __restrict__ X, const unsigned short* __restrict__ Wt_hi,
    const unsigned short* __restrict__ Wt_lo, const float* __restrict__ bias,
    unsigned short* __restrict__ Ch, int M)
{
  const int tid = threadIdx.x;
  const int lane = tid & 63;
  const int wv = tid >> 6;
  const int ml = lane & 15;
  const int kg = lane >> 4;
  const int R0 = blockIdx.x * 64;

  __shared__ uint32_t sA[2][1024];
  __shared__ float sC[4][32][36];

  const unsigned short* bhp[2];
  const unsigned short* blp[2];
  #pragma unroll
  for (int nt = 0; nt < 2; ++nt){
    int n = wv*32 + nt*16 + ml;
    bhp[nt] = Wt_hi + (size_t)n*64 + kg*8;
    blp[nt] = Wt_lo + (size_t)n*64 + kg*8;
  }

  {
    int row = tid >> 2, kq = tid & 3;
    int gr = R0 + row; gr = gr < M ? gr : M-1;
    const float4* xp = (const float4*)(X + (size_t)gr*64 + kq*16);
    int sub = kq >> 1;
    #pragma unroll
    for (int i = 0; i < 4; ++i){
      float4 v = xp[i];
      __half2 h0 = __floats2half2_rn(v.x, v.y);
      __half2 h1 = __floats2half2_rn(v.z, v.w);
      int slot = (kq & 1)*2 + (i >> 1);
      int slot_s = slot ^ ((row >> 1) & 3);
      int byte = row*64 + slot_s*16 + (i & 1)*8;
      *(uint2*)((char*)&sA[sub][0] + byte) = make_uint2(*(uint32_t*)&h0, *(uint32_t*)&h1);
    }
  }
  __syncthreads();                      // cross-wave sA staging

  f32x4 accH[4][2], accL[4][2];
  #pragma unroll
  for (int mt = 0; mt < 4; ++mt)
    #pragma unroll
    for (int nt = 0; nt < 2; ++nt){
      accH[mt][nt] = (f32x4){0.f,0.f,0.f,0.f};
      accL[mt][nt] = (f32x4){0.f,0.f,0.f,0.f};
    }

  #pragma unroll
  for (int sc = 0; sc < 2; ++sc){
    u4h8 bh[2], bl[2];
    #pragma unroll
    for (int nt = 0; nt < 2; ++nt){
      bh[nt].u = *(const uint4*)(bhp[nt] + sc*32);
      bl[nt].u = *(const uint4*)(blp[nt] + sc*32);
    }
    const char* buf = (const char*)&sA[sc][0];
    #pragma unroll
    for (int mt = 0; mt < 4; ++mt){
      int row = mt*16 + ml;
      int ba = row*64 + ((kg ^ ((row >> 1) & 3)) * 16);
      u4h8 A_;
      A_.u = *(const uint4*)(buf + ba);
      #pragma unroll
      for (int nt = 0; nt < 2; ++nt){
        accH[mt][nt] = __builtin_amdgcn_mfma_f32_16x16x32_f16(A_.h, bh[nt].h, accH[mt][nt], 0, 0, 0);
        accL[mt][nt] = __builtin_amdgcn_mfma_f32_16x16x32_f16(A_.h, bl[nt].h, accL[mt][nt], 0, 0, 0);
      }
    }
  }

  // epilogue: sC[wv] is wave-private -> no barriers needed (wave-internal lgkmcnt)
  float bv[2] = { bias[wv*32 + ml], bias[wv*32 + 16 + ml] };
  #pragma unroll
  for (int p = 0; p < 2; ++p){
    #pragma unroll
    for (int mh = 0; mh < 2; ++mh){
      int mt = p*2 + mh;
      #pragma unroll
      for (int nt = 0; nt < 2; ++nt){
        #pragma unroll
        for (int r = 0; r < 4; ++r){
          float v = accH[mt][nt][r] + accL[mt][nt][r] * 9.765625e-4f;
          v = lrelu(v + bv[nt]);
          sC[wv][mh*16 + kg*4 + r][nt*16 + ml] = v;
        }
      }
    }
    #pragma unroll
    for (int j = 0; j < 4; ++j){
      int row_l = j*8 + (lane >> 3);
      int c4 = (lane & 7) * 4;
      int grow = R0 + p*32 + row_l;
      if (grow < M){
        float4 v = *(const float4*)&sC[wv][row_l][c4];
        int gcol = wv*32 + c4;
        __half2 h0 = __floats2half2_rn(v.x, v.y);
        __half2 h1 = __floats2half2_rn(v.z, v.w);
        *(uint2*)(Ch + (size_t)grow*128 + gcol) = make_uint2(*(uint32_t*)&h0, *(uint32_t*)&h1);
      }
    }
  }
}

// ============ main MFMA GEMM: C[M,128] = A[M,128] @ W, f16 dual-acc ============
// LDS: sA (16 KB staging) UNIONed with sC (18 KB epilogue bounce) -> 20.5 KB total.
// B re-loaded per sub-chunk from L2; sC bounce is wave-private (no barriers).
template<int OUTMODE, bool DOTA, bool DOTB>
__global__ __launch_bounds__(256, 4) void gemm_mfma(
    const unsigned short* __restrict__ Ah, const unsigned short* __restrict__ Wt_hi,
    const unsigned short* __restrict__ Wt_lo,
    const float* __restrict__ va, const float* __restrict__ vb,
    unsigned short* __restrict__ Ch,
    float* __restrict__ outa, float* __restrict__ outb, int M)
{
  constexpr int K = 128;
  const int tid = threadIdx.x;
  const int lane = tid & 63;
  const int wv = tid >> 6;
  const int ml = lane & 15;
  const int kg = lane >> 4;
  const int R0 = blockIdx.x * 64;

  __shared__ char smem[18432];       // union: sA[4][1024] u32 (16 KB) / sC[4][32][36] f32 (18 KB)
  __shared__ float sd[4][64][2];
  uint32_t* sA = (uint32_t*)smem;
  typedef float sC_t[32][36];
  sC_t* sC = (sC_t*)smem;

  const unsigned short* bhp[2];
  const unsigned short* blp[2];
  #pragma unroll
  for (int nt = 0; nt < 2; ++nt){
    int n = wv*32 + nt*16 + ml;
    bhp[nt] = Wt_hi + (size_t)n*K + kg*8;
    blp[nt] = Wt_lo + (size_t)n*K + kg*8;
  }

  auto STAGE = [&](int ch){
    #pragma unroll
    for (int j = 0; j < 2; ++j){
      int sc = ch*2 + j;
      int o = tid*16;
      int row = o >> 6;
      int t = (o >> 4) & 3;
      int gr = R0 + row; gr = gr < M ? gr : M-1;
      int jj = t ^ ((row >> 1) & 3);
      const char* src = (const char*)(Ah + (size_t)gr*K + sc*32 + jj*8);
      char* dst = (char*)sA + ((ch & 1)*2 + j)*4096 + wv*1024;
      __builtin_amdgcn_global_load_lds(
          (const __attribute__((address_space(1))) void*)src,
          (__attribute__((address_space(3))) void*)dst, 16, 0, 0);
    }
  };

  f32x4 accH[4][2], accL[4][2];
  #pragma unroll
  for (int mt = 0; mt < 4; ++mt)
    #pragma unroll
    for (int nt = 0; nt < 2; ++nt){
      accH[mt][nt] = (f32x4){0.f,0.f,0.f,0.f};
      accL[mt][nt] = (f32x4){0.f,0.f,0.f,0.f};
    }

  STAGE(0);
  __syncthreads();

  #pragma unroll
  for (int ch = 0; ch < 2; ++ch){
    if (ch == 0) STAGE(1);
    #pragma unroll
    for (int js = 0; js < 2; ++js){
      int sc = ch*2 + js;
      u4h8 bh[2], bl[2];
      #pragma unroll
      for (int nt = 0; nt < 2; ++nt){
        bh[nt].u = *(const uint4*)(bhp[nt] + sc*32);
        bl[nt].u = *(const uint4*)(blp[nt] + sc*32);
      }
      const char* buf = (const char*)sA + ((ch & 1)*2 + js)*4096;
      #pragma unroll
      for (int mt = 0; mt < 4; ++mt){
        int row = mt*16 + ml;
        int ba = row*64 + ((kg ^ ((row >> 1) & 3)) * 16);
        u4h8 A_;
        A_.u = *(const uint4*)(buf + ba);
        #pragma unroll
        for (int nt = 0; nt < 2; ++nt){
          accH[mt][nt] = __builtin_amdgcn_mfma_f32_16x16x32_f16(A_.h, bh[nt].h, accH[mt][nt], 0, 0, 0);
          accL[mt][nt] = __builtin_amdgcn_mfma_f32_16x16x32_f16(A_.h, bl[nt].h, accL[mt][nt], 0, 0, 0);
        }
      }
    }
    __syncthreads();                  // ch0: STAGE(1) done; ch1: sA free before sC overwrite
  }

  #pragma unroll
  for (int mt = 0; mt < 4; ++mt)
    #pragma unroll
    for (int nt = 0; nt < 2; ++nt)
      accH[mt][nt] = accH[mt][nt] + accL[mt][nt] * 9.765625e-4f;

  if constexpr (DOTA || DOTB){
    float vaL[2] = {0.f,0.f}, vbL[2] = {0.f,0.f};
    if constexpr (DOTA){ vaL[0] = va[wv*32 + ml]; vaL[1] = va[wv*32 + 16 + ml]; }
    if constexpr (DOTB){ vbL[0] = vb[wv*32 + ml]; vbL[1] = vb[wv*32 + 16 + ml]; }
    #pragma unroll
    for (int mt = 0; mt < 4; ++mt){
      #pragma unroll
      for (int r = 0; r < 4; ++r){
        float pa = 0.f, pb = 0.f;
        #pragma unroll
        for (int nt = 0; nt < 2; ++nt){
          float v = accH[mt][nt][r];
          if constexpr (DOTA) pa = fmaf(v, vaL[nt], pa);
          if constexpr (DOTB) pb = fmaf(v, vbL[nt], pb);
        }
        #pragma unroll
        for (int o = 8; o; o >>= 1){
          if constexpr (DOTA) pa += __shfl_xor(pa, o, 64);
          if constexpr (DOTB) pb += __shfl_xor(pb, o, 64);
        }
        if (ml == 0){
          int rl = mt*16 + kg*4 + r;
          sd[wv][rl][0] = pa;
          sd[wv][rl][1] = pb;
        }
      }
    }
    __syncthreads();                  // cross-wave sd reduce (keep)
    if (tid < 64){
      int row = R0 + tid;
      if (row < M){
        if constexpr (DOTA)
          outa[row] = sd[0][tid][0] + sd[1][tid][0] + sd[2][tid][0] + sd[3][tid][0];
        if constexpr (DOTB)
          outb[row] = sd[0][tid][1] + sd[1][tid][1] + sd[2][tid][1] + sd[3][tid][1];
      }
    }
  }

  // sC bounce: wave-private region, wave-internal ordering only -> no barriers
  if constexpr (OUTMODE == 2){
    #pragma unroll
    for (int p = 0; p < 2; ++p){
      #pragma unroll
      for (int mh = 0; mh < 2; ++mh){
        int mt = p*2 + mh;
        #pragma unroll
        for (int nt = 0; nt < 2; ++nt){
          #pragma unroll
          for (int r = 0; r < 4; ++r)
            sC[wv][mh*16 + kg*4 + r][nt*16 + ml] = accH[mt][nt][r];
        }
      }
      #pragma unroll
      for (int j = 0; j < 4; ++j){
        int row_l = j*8 + (lane >> 3);
        int c4 = (lane & 7) * 4;
        int grow = R0 + p*32 + row_l;
        if (grow < M){
          float4 v = *(const float4*)&sC[wv][row_l][c4];
          int gcol = wv*32 + c4;
          __half2 h0 = __floats2half2_rn(v.x, v.y);
          __half2 h1 = __floats2half2_rn(v.z, v.w);
          *(uint2*)(Ch + (size_t)grow*128 + gcol) = make_uint2(*(uint32_t*)&h0, *(uint32_t*)&h1);
        }
      }
    }
  }
}

// ============ CSR build (2 edges/thread) ============
__global__ void hist_k(const int* __restrict__ dstv, int* __restrict__ deg, int E){
  int e = (blockIdx.x*256 + threadIdx.x)*2;
  if (e + 1 < E){
    int2 d = *(const int2*)(dstv + e);
    atomicAdd(&deg[d.x], 1);
    atomicAdd(&deg[d.y], 1);
  } else if (e < E){
    atomicAdd(&deg[dstv[e]], 1);
  }
}

// single-pass scan with decoupled lookback (ticket-ordered, all blocks resident)
__global__ void scan_onepass(const int* __restrict__ deg, int* __restrict__ rp,
    int* __restrict__ cur, unsigned long long* __restrict__ bstat,
    int* __restrict__ bctr, int n, int E)
{
  __shared__ int sbid;
  __shared__ int swsum[4];
  __shared__ int sprev;
  if (threadIdx.x == 0) sbid = atomicAdd(bctr, 1);
  __syncthreads();
  const int bid = sbid;
  int i = bid*256 + threadIdx.x;
  int lane = threadIdx.x & 63, wv = threadIdx.x >> 6;
  int v = (i < n) ? deg[i] : 0;
  int inc = v;
  #pragma unroll
  for (int o = 1; o < 64; o <<= 1){
    int u = __shfl_up(inc, o, 64);
    if (lane >= o) inc += u;
  }
  if (lane == 63) swsum[wv] = inc;
  __syncthreads();
  if (threadIdx.x == 0){
    int bsum = swsum[0]+swsum[1]+swsum[2]+swsum[3];
    atomicExch(&bstat[bid], (1ull << 62) | (unsigned long long)(unsigned)bsum);
    int prev = 0;
    for (int j = bid - 1; j >= 0; --j){
      unsigned long long s;
      do { s = atomicAdd(&bstat[j], 0ull); } while ((s >> 62) == 0);
      prev += (int)(s & 0xffffffffull);
      if ((s >> 62) == 2) break;
    }
    atomicExch(&bstat[bid], (2ull << 62) | (unsigned long long)(unsigned)(prev + bsum));
    sprev = prev;
  }
  __syncthreads();
  int woff = sprev;
  for (int wq = 0; wq < wv; ++wq) woff += swsum[wq];
  int excl = woff + inc - v;
  if (i < n){ rp[i] = excl; cur[i] = excl; }
  if (bid == 0 && threadIdx.x == 0) rp[n] = E;
}

__global__ void scatter_k(const int* __restrict__ srcv, const int* __restrict__ dstv,
                          int* __restrict__ cur, int* __restrict__ ssorted, int E){
  int e = (blockIdx.x*256 + threadIdx.x)*2;
  if (e + 1 < E){
    int2 s = *(const int2*)(srcv + e);
    int2 d = *(const int2*)(dstv + e);
    int p0 = atomicAdd(&cur[d.x], 1);
    ssorted[p0] = s.x;
    int p1 = atomicAdd(&cur[d.y], 1);
    ssorted[p1] = s.y;
  } else if (e < E){
    int p = atomicAdd(&cur[dstv[e]], 1);
    ssorted[p] = srcv[e];
  }
}

// ============ fused segment softmax + aggregation: 16-lane group per dst node ============
// 4 dst/wave. Lane covers 8 features (uint4 = 16B loads). Inner loop: unconditional
// 8-wide batches (ghost lanes have alpha==0, sid==0) -> 8 gathers in flight.
__global__ __launch_bounds__(256) void gat_agg(const int* __restrict__ ssorted,
    const int* __restrict__ rp,
    const float* __restrict__ asn, const float* __restrict__ adn,
    const uint4* __restrict__ hsv, const float* __restrict__ bias,
    uint4* __restrict__ outv, int Nn)
{
  const int lane = threadIdx.x & 63;
  const int wv = threadIdx.x >> 6;
  const int l16 = lane & 15;
  const int gbase = lane & 48;
  const int d = blockIdx.x*16 + wv*4 + (lane >> 4);
  const bool valid = d < Nn;
  const int dc = valid ? d : Nn-1;
  const int lo = rp[dc], hi = rp[dc+1];
  const int deg = valid ? (hi - lo) : 0;
  const float ad = adn[dc];
  float acc[8] = {0.f,0.f,0.f,0.f,0.f,0.f,0.f,0.f};

  const bool fast = (deg <= 16);
  const int fdeg = fast ? deg : 0;
  int mdeg = fdeg;
  mdeg = max(mdeg, __shfl_xor(mdeg, 16, 64));
  mdeg = max(mdeg, __shfl_xor(mdeg, 32, 64));
  const int nb = (mdeg + 7) & ~7;          // wave-uniform: 0, 8, or 16

  int sid = 0; float lg = -1e30f;
  if (l16 < fdeg){
    sid = ssorted[lo + l16];
    lg = lrelu(asn[sid] + ad);
  }
  float m = lg;
  m = fmaxf(m, __shfl_xor(m, 8, 64));
  m = fmaxf(m, __shfl_xor(m, 4, 64));
  m = fmaxf(m, __shfl_xor(m, 2, 64));
  m = fmaxf(m, __shfl_xor(m, 1, 64));
  float p = (l16 < fdeg) ? __expf(lg - m) : 0.f;
  float s = p;
  s += __shfl_xor(s, 8, 64);
  s += __shfl_xor(s, 4, 64);
  s += __shfl_xor(s, 2, 64);
  s += __shfl_xor(s, 1, 64);
  float alpha = p * (1.f / (s + 1e-16f));

  for (int i = 0; i < nb; i += 8){
    float al[8]; int sd[8]; uint4 v[8];
    #pragma unroll
    for (int j = 0; j < 8; ++j){
      al[j] = __shfl(alpha, gbase + i + j, 64);
      sd[j] = __shfl(sid, gbase + i + j, 64);
    }
    #pragma unroll
    for (int j = 0; j < 8; ++j)
      v[j] = hsv[(size_t)sd[j]*16 + l16];
    #pragma unroll
    for (int j = 0; j < 8; ++j){
      float2 f0 = __half22float2(*(__half2*)&v[j].x);
      float2 f1 = __half22float2(*(__half2*)&v[j].y);
      float2 f2 = __half22float2(*(__half2*)&v[j].z);
      float2 f3 = __half22float2(*(__half2*)&v[j].w);
      acc[0] = fmaf(al[j], f0.x, acc[0]); acc[1] = fmaf(al[j], f0.y, acc[1]);
      acc[2] = fmaf(al[j], f1.x, acc[2]); acc[3] = fmaf(al[j], f1.y, acc[3]);
      acc[4] = fmaf(al[j], f2.x, acc[4]); acc[5] = fmaf(al[j], f2.y, acc[5]);
      acc[6] = fmaf(al[j], f3.x, acc[6]); acc[7] = fmaf(al[j], f3.y, acc[7]);
    }
  }

  if (!fast){                                // rare: deg > 16
    float mg = -1e30f;
    for (int e = l16; e < deg; e += 16){
      int sd = ssorted[lo + e];
      mg = fmaxf(mg, lrelu(asn[sd] + ad));
    }
    mg = fmaxf(mg, __shfl_xor(mg, 8, 64));
    mg = fmaxf(mg, __shfl_xor(mg, 4, 64));
    mg = fmaxf(mg, __shfl_xor(mg, 2, 64));
    mg = fmaxf(mg, __shfl_xor(mg, 1, 64));
    float sg = 0.f;
    for (int e = l16; e < deg; e += 16){
      int sd = ssorted[lo + e];
      sg += __expf(lrelu(asn[sd] + ad) - mg);
    }
    sg += __shfl_xor(sg, 8, 64);
    sg += __shfl_xor(sg, 4, 64);
    sg += __shfl_xor(sg, 2, 64);
    sg += __shfl_xor(sg, 1, 64);
    float inv = 1.f / (sg + 1e-16f);
    for (int e = 0; e < deg; ++e){
      int sd = ssorted[lo + e];
      float a = __expf(lrelu(asn[sd] + ad) - mg) * inv;
      uint4 v = hsv[(size_t)sd*16 + l16];
      float2 f0 = __half22float2(*(__half2*)&v.x);
      float2 f1 = __half22float2(*(__half2*)&v.y);
      float2 f2 = __half22float2(*(__half2*)&v.z);
      float2 f3 = __half22float2(*(__half2*)&v.w);
      acc[0] = fmaf(a, f0.x, acc[0]); acc[1] = fmaf(a, f0.y, acc[1]);
      acc[2] = fmaf(a, f1.x, acc[2]); acc[3] = fmaf(a, f1.y, acc[3]);
      acc[4] = fmaf(a, f2.x, acc[4]); acc[5] = fmaf(a, f2.y, acc[5]);
      acc[6] = fmaf(a, f3.x, acc[6]); acc[7] = fmaf(a, f3.y, acc[7]);
    }
  }

  if (valid){
    float4 b0 = ((const float4*)bias)[l16*2];
    float4 b1 = ((const float4*)bias)[l16*2 + 1];
    __half2 h0 = __floats2half2_rn(elu1(acc[0]+b0.x), elu1(acc[1]+b0.y));
    __half2 h1 = __floats2half2_rn(elu1(acc[2]+b0.z), elu1(acc[3]+b0.w));
    __half2 h2 = __floats2half2_rn(elu1(acc[4]+b1.x), elu1(acc[5]+b1.y));
    __half2 h3 = __floats2half2_rn(elu1(acc[6]+b1.z), elu1(acc[7]+b1.w));
    outv[(size_t)d*16 + l16] = make_uint4(*(uint32_t*)&h0, *(uint32_t*)&h1,
                                          *(uint32_t*)&h2, *(uint32_t*)&h3);
  }
}

// ============ graph pooling: 16-lane group per graph ============
__global__ __launch_bounds__(256) void pool_relu(const uint4* __restrict__ hv,
    const int* __restrict__ batch, uint4* __restrict__ ptail, int Nn, int G)
{
  const int lane = threadIdx.x & 63;
  const int wv = threadIdx.x >> 6;
  const int l16 = lane & 15;
  const int g = blockIdx.x*16 + wv*4 + (lane >> 4);
  if (g >= G) return;
  const int lo = lower_bound_i(batch, Nn, g);
  const int hi = lower_bound_i(batch, Nn, g + 1);
  float acc[8] = {0.f,0.f,0.f,0.f,0.f,0.f,0.f,0.f};
  for (int i = lo; i < hi; ++i){
    uint4 v = hv[(size_t)i*16 + l16];
    float2 f0 = __half22float2(*(__half2*)&v.x);
    float2 f1 = __half22float2(*(__half2*)&v.y);
    float2 f2 = __half22float2(*(__half2*)&v.z);
    float2 f3 = __half22float2(*(__half2*)&v.w);
    acc[0] += f0.x; acc[1] += f0.y; acc[2] += f1.x; acc[3] += f1.y;
    acc[4] += f2.x; acc[5] += f2.y; acc[6] += f3.x; acc[7] += f3.y;
  }
  __half2 h0 = __floats2half2_rn(fmaxf(acc[0],0.f), fmaxf(acc[1],0.f));
  __half2 h1 = __floats2half2_rn(fmaxf(acc[2],0.f), fmaxf(acc[3],0.f));
  __half2 h2 = __floats2half2_rn(fmaxf(acc[4],0.f), fmaxf(acc[5],0.f));
  __half2 h3 = __floats2half2_rn(fmaxf(acc[6],0.f), fmaxf(acc[7],0.f));
  ptail[(size_t)g*16 + l16] = make_uint4(*(uint32_t*)&h0, *(uint32_t*)&h1,
                                         *(uint32_t*)&h2, *(uint32_t*)&h3);
}

// ============ molecular GAT aggregate + final linear (fused) ============
__global__ __launch_bounds__(128) void mol_agg(const float* __restrict__ as2,
    const float* __restrict__ ad2, const unsigned short* __restrict__ hs2,
    const int* __restrict__ batch, const float* __restrict__ bias,
    const float* __restrict__ W2, const float* __restrict__ b2,
    float* __restrict__ out, int Nn)
{
  const int g = blockIdx.x;
  const int c = threadIdx.x;
  __shared__ int sb[2];
  __shared__ float red[2];
  if (c < 2) sb[c] = lower_bound_i(batch, Nn, g + c);
  __syncthreads();
  const int lo = sb[0], hi = sb[1];
  const float ad = ad2[g];

  float mt = -1e30f;
  for (int i = lo + c; i < hi; i += 128) mt = fmaxf(mt, lrelu(as2[i] + ad));
  #pragma unroll
  for (int o = 32; o; o >>= 1) mt = fmaxf(mt, __shfl_xor(mt, o, 64));
  if ((c & 63) == 0) red[c >> 6] = mt;
  __syncthreads();
  const float m = fmaxf(red[0], red[1]);

  float st = 0.f;
  for (int i = lo + c; i < hi; i += 128) st += __expf(lrelu(as2[i] + ad) - m);
  #pragma unroll
  for (int o = 32; o; o >>= 1) st += __shfl_xor(st, o, 64);
  __syncthreads();
  if ((c & 63) == 0) red[c >> 6] = st;
  __syncthreads();
  const float inv = 1.f / (red[0] + red[1] + 1e-16f);

  float acc = 0.f;
  for (int i = lo; i < hi; ++i){
    float wgt = __expf(lrelu(as2[i] + ad) - m) * inv;
    acc = fmaf(wgt, __half2float(__ushort_as_half(hs2[(size_t)i*128 + c])), acc);
  }
  float v = elu1(acc + bias[c]);

  float r = v * W2[c];
  #pragma unroll
  for (int o = 32; o; o >>= 1) r += __shfl_xor(r, o, 64);
  __syncthreads();
  if ((c & 63) == 0) red[c >> 6] = r;
  __syncthreads();
  if (c == 0) out[g] = red[0] + red[1] + b2[0];
}

extern "C" void kernel_launch(void* const* d_in, const int* in_sizes, int n_in,
                              void* d_out, int out_size, void* d_ws, size_t ws_size,
                              hipStream_t stream)
{
  const float* x      = (const float*)d_in[0];
  const int*   ei     = (const int*)  d_in[1];
  const int*   batch  = (const int*)  d_in[2];
  const float* W1     = (const float*)d_in[3];
  const float* b1     = (const float*)d_in[4];
  const float* gW     = (const float*)d_in[5];
  const float* g_asrc = (const float*)d_in[6];
  const float* g_adst = (const float*)d_in[7];
  const float* g_b    = (const float*)d_in[8];
  const float* mW     = (const float*)d_in[9];
  const float* m_asrc = (const float*)d_in[10];
  const float* m_adst = (const float*)d_in[11];
  const float* m_b    = (const float*)d_in[12];
  const float* W2     = (const float*)d_in[13];
  const float* b2     = (const float*)d_in[14];

  const int Nn = in_sizes[0] / 64;            // 100000
  const int E  = in_sizes[1] / 2;             // 400000
  const int G  = out_size;                    // 5000
  const int NL = in_sizes[5] / (128*128);     // 3
  const int M2 = Nn + G;
  const int* srcv = ei;
  const int* dstv = ei + E;

  char* w = (char*)d_ws;
  unsigned short* h16 = (unsigned short*)w; w += (size_t)(M2+64)*128*2;
  unsigned short* hsR = (unsigned short*)w; w += (size_t)(M2+64)*128*2;
  float* asO      = (float*)w; w += (size_t)(M2+64)*4;
  float* adO      = (float*)w; w += (size_t)(M2+64)*4;
  int*   deg      = (int*)w;   w += (size_t)Nn*4;
  int*   rp       = (int*)w;   w += (size_t)(Nn+64)*4;
  int*   cur      = (int*)w;   w += (size_t)Nn*4;
  int*   ssorted  = (int*)w;   w += (size_t)E*4;
  unsigned long long* bstat = (unsigned long long*)w; w += 512*8;
  int*   bctr     = (int*)w;   w += 64;
  unsigned short* w1h = (unsigned short*)w; w += 64*128*2;
  unsigned short* w1l = (unsigned short*)w; w += 64*128*2;
  unsigned short* gwh = (unsigned short*)w; w += (size_t)NL*128*128*2;
  unsigned short* gwl = (unsigned short*)w; w += (size_t)NL*128*128*2;
  unsigned short* mwh = (unsigned short*)w; w += 128*128*2;
  unsigned short* mwl = (unsigned short*)w; w += 128*128*2;

  const int nscan = (Nn + 255)/256;
  const int nrt = (Nn + 63)/64;
  const int mrt = (M2 + 63)/64;
  const int ne2 = (E/2 + 255)/256;

  // ---- prep (weights + zero CSR/scan state) ----
  wprep_all<<<nscan, 256, 0, stream>>>(W1, gW, mW, w1h, w1l, gwh, gwl, mwh, mwl,
                                       deg, bstat, bctr, Nn, NL*16384, nscan);

  // ---- CSR build ----
  hist_k<<<ne2, 256, 0, stream>>>(dstv, deg, E);
  scan_onepass<<<nscan, 256, 0, stream>>>(deg, rp, cur, bstat, bctr, Nn, E);
  scatter_k<<<ne2, 256, 0, stream>>>(srcv, dstv, cur, ssorted, E);

  // ---- lin1 ----
  gemm_lin1<<<nrt, 256, 0, stream>>>(x, w1h, w1l, b1, h16, Nn);

  // ---- 3 GAT layers ----
  for (int l = 0; l < NL; ++l){
    gemm_mfma<2, true, true><<<nrt, 256, 0, stream>>>(
        h16, gwh + (size_t)l*128*128, gwl + (size_t)l*128*128,
        g_asrc + l*128, g_adst + l*128, hsR, asO, adO, Nn);
    gat_agg<<<(Nn+15)/16, 256, 0, stream>>>(ssorted, rp, asO, adO,
        (const uint4*)hsR, g_b + l*128, (uint4*)h16, Nn);
  }

  // ---- readout ----
  pool_relu<<<(G+15)/16, 256, 0, stream>>>((const uint4*)h16, batch,
      (uint4*)(h16 + (size_t)Nn*128), Nn, G);
  gemm_mfma<2, true, true><<<mrt, 256, 0, stream>>>(
      h16, mwh, mwl, m_asrc, m_adst, hsR, asO, adO, M2);
  mol_agg<<<G, 128, 0, stream>>>(asO, adO + Nn, hsR, batch, m_b, W2, b2, (float*)d_out, Nn);
}

// Round 12
// 301.901 us; speedup vs baseline: 1.0400x; 1.0400x over previous
//
#include <hip/hip_runtime.h>
#include <hip/hip_fp16.h>
#include <math.h>
#include <stdint.h>

#define DEV __device__ __forceinline__

using f32x4 = __attribute__((ext_vector_type(4))) float;
using half8 = __attribute__((ext_vector_type(8))) _Float16;
typedef union { uint4 u; half8 h; } u4h8;

DEV float lrelu(float x){ return x > 0.f ? x : 0.01f*x; }
DEV float elu1(float x){ return x > 0.f ? x : __expf(x)-1.f; }

DEV int lower_bound_i(const int* __restrict__ a, int n, int key){
  int lo = 0, hi = n;
  while (lo < hi){ int mid = (lo+hi)>>1; if (a[mid] < key) lo = mid+1; else hi = mid; }
  return lo;
}

// ============ combined prep: all weight splits + zero CSR/scan state ============
DEV void wsplit(float v, unsigned short* __restrict__ H, unsigned short* __restrict__ L, size_t o){
  __half h = __float2half_rn(v);
  float lo = (v - __half2float(h)) * 1024.f;
  H[o] = __half_as_ushort(h);
  L[o] = __half_as_ushort(__float2half_rn(lo));
}

__global__ void wprep_all(const float* __restrict__ W1, const float* __restrict__ gW,
    const float* __restrict__ mW,
    unsigned short* __restrict__ w1h, unsigned short* __restrict__ w1l,
    unsigned short* __restrict__ gwh, unsigned short* __restrict__ gwl,
    unsigned short* __restrict__ mwh, unsigned short* __restrict__ mwl,
    int* __restrict__ deg, unsigned long long* __restrict__ bstat,
    int* __restrict__ bctr, int Nn, int nG, int nscan)
{
  int i = blockIdx.x*256 + threadIdx.x;
  if (i < Nn) deg[i] = 0;
  if (i < nscan) bstat[i] = 0ull;
  if (i == 0) *bctr = 0;
  if (i < 8192){                       // W1 [64][128] -> [128][64]
    int k = i >> 7, n = i & 127;
    wsplit(W1[i], w1h, w1l, (size_t)n*64 + k);
  }
  if (i < nG){                         // gW [NL][128][128] -> [NL][128][128]T
    int mat = i >> 14; int rem = i & 16383;
    int k = rem >> 7, n = rem & 127;
    wsplit(gW[i], gwh, gwl, (size_t)mat*16384 + (size_t)n*128 + k);
  }
  if (i < 16384){                      // mW
    int k = i >> 7, n = i & 127;
    wsplit(mW[i], mwh, mwl, (size_t)n*128 + k);
  }
}

// ============ lin1 GEMM: h = lrelu(x[M,64] @ W1 + b1) -> fp16 (x converted in-kernel) ============
__global__ __launch_bounds__(256, 3) void gemm_lin1(
    const float* __restrict__ X, const unsigned short* __restrict__ Wt_hi,
    const unsigned short* __restrict__ Wt_lo, const float* __restrict__ bias,
    unsigned short* __restrict__ Ch, int M)
{
  const int tid = threadIdx.x;
  const int lane = tid & 63;
  const int wv = tid >> 6;
  const int ml = lane & 15;
  const int kg = lane >> 4;
  const int R0 = blockIdx.x * 64;

  __shared__ uint32_t sA[2][1024];
  __shared__ float sC[4][32][36];

  const unsigned short* bhp[2];
  const unsigned short* blp[2];
  #pragma unroll
  for (int nt = 0; nt < 2; ++nt){
    int n = wv*32 + nt*16 + ml;
    bhp[nt] = Wt_hi + (size_t)n*64 + kg*8;
    blp[nt] = Wt_lo + (size_t)n*64 + kg*8;
  }

  {
    int row = tid >> 2, kq = tid & 3;
    int gr = R0 + row; gr = gr < M ? gr : M-1;
    const float4* xp = (const float4*)(X + (size_t)gr*64 + kq*16);
    int sub = kq >> 1;
    #pragma unroll
    for (int i = 0; i < 4; ++i){
      float4 v = xp[i];
      __half2 h0 = __floats2half2_rn(v.x, v.y);
      __half2 h1 = __floats2half2_rn(v.z, v.w);
      int slot = (kq & 1)*2 + (i >> 1);
      int slot_s = slot ^ ((row >> 1) & 3);
      int byte = row*64 + slot_s*16 + (i & 1)*8;
      *(uint2*)((char*)&sA[sub][0] + byte) = make_uint2(*(uint32_t*)&h0, *(uint32_t*)&h1);
    }
  }
  __syncthreads();                      // cross-wave sA staging

  f32x4 accH[4][2], accL[4][2];
  #pragma unroll
  for (int mt = 0; mt < 4; ++mt)
    #pragma unroll
    for (int nt = 0; nt < 2; ++nt){
      accH[mt][nt] = (f32x4){0.f,0.f,0.f,0.f};
      accL[mt][nt] = (f32x4){0.f,0.f,0.f,0.f};
    }

  #pragma unroll
  for (int sc = 0; sc < 2; ++sc){
    u4h8 bh[2], bl[2];
    #pragma unroll
    for (int nt = 0; nt < 2; ++nt){
      bh[nt].u = *(const uint4*)(bhp[nt] + sc*32);
      bl[nt].u = *(const uint4*)(blp[nt] + sc*32);
    }
    const char* buf = (const char*)&sA[sc][0];
    #pragma unroll
    for (int mt = 0; mt < 4; ++mt){
      int row = mt*16 + ml;
      int ba = row*64 + ((kg ^ ((row >> 1) & 3)) * 16);
      u4h8 A_;
      A_.u = *(const uint4*)(buf + ba);
      #pragma unroll
      for (int nt = 0; nt < 2; ++nt){
        accH[mt][nt] = __builtin_amdgcn_mfma_f32_16x16x32_f16(A_.h, bh[nt].h, accH[mt][nt], 0, 0, 0);
        accL[mt][nt] = __builtin_amdgcn_mfma_f32_16x16x32_f16(A_.h, bl[nt].h, accL[mt][nt], 0, 0, 0);
      }
    }
  }

  // epilogue: sC[wv] is wave-private -> no barriers needed (wave-internal lgkmcnt)
  float bv[2] = { bias[wv*32 + ml], bias[wv*32 + 16 + ml] };
  #pragma unroll
  for (int p = 0; p < 2; ++p){
    #pragma unroll
    for (int mh = 0; mh < 2; ++mh){
      int mt = p*2 + mh;
      #pragma unroll
      for (int nt = 0; nt < 2; ++nt){
        #pragma unroll
        for (int r = 0; r < 4; ++r){
          float v = accH[mt][nt][r] + accL[mt][nt][r] * 9.765625e-4f;
          v = lrelu(v + bv[nt]);
          sC[wv][mh*16 + kg*4 + r][nt*16 + ml] = v;
        }
      }
    }
    #pragma unroll
    for (int j = 0; j < 4; ++j){
      int row_l = j*8 + (lane >> 3);
      int c4 = (lane & 7) * 4;
      int grow = R0 + p*32 + row_l;
      if (grow < M){
        float4 v = *(const float4*)&sC[wv][row_l][c4];
        int gcol = wv*32 + c4;
        __half2 h0 = __floats2half2_rn(v.x, v.y);
        __half2 h1 = __floats2half2_rn(v.z, v.w);
        *(uint2*)(Ch + (size_t)grow*128 + gcol) = make_uint2(*(uint32_t*)&h0, *(uint32_t*)&h1);
      }
    }
  }
}

// ============ main MFMA GEMM: C[M,128] = A[M,128] @ W, f16 dual-acc ============
// LDS: sA (16 KB staging) UNIONed with sC (18 KB epilogue bounce) -> 20.5 KB total.
// B re-loaded per sub-chunk from L2; sC bounce is wave-private (no barriers).
template<int OUTMODE, bool DOTA, bool DOTB>
__global__ __launch_bounds__(256, 4) void gemm_mfma(
    const unsigned short* __restrict__ Ah, const unsigned short* __restrict__ Wt_hi,
    const unsigned short* __restrict__ Wt_lo,
    const float* __restrict__ va, const float* __restrict__ vb,
    unsigned short* __restrict__ Ch,
    float* __restrict__ outa, float* __restrict__ outb, int M)
{
  constexpr int K = 128;
  const int tid = threadIdx.x;
  const int lane = tid & 63;
  const int wv = tid >> 6;
  const int ml = lane & 15;
  const int kg = lane >> 4;
  const int R0 = blockIdx.x * 64;

  __shared__ char smem[18432];       // union: sA[4][1024] u32 (16 KB) / sC[4][32][36] f32 (18 KB)
  __shared__ float sd[4][64][2];
  uint32_t* sA = (uint32_t*)smem;
  typedef float sC_t[32][36];
  sC_t* sC = (sC_t*)smem;

  const unsigned short* bhp[2];
  const unsigned short* blp[2];
  #pragma unroll
  for (int nt = 0; nt < 2; ++nt){
    int n = wv*32 + nt*16 + ml;
    bhp[nt] = Wt_hi + (size_t)n*K + kg*8;
    blp[nt] = Wt_lo + (size_t)n*K + kg*8;
  }

  auto STAGE = [&](int ch){
    #pragma unroll
    for (int j = 0; j < 2; ++j){
      int sc = ch*2 + j;
      int o = tid*16;
      int row = o >> 6;
      int t = (o >> 4) & 3;
      int gr = R0 + row; gr = gr < M ? gr : M-1;
      int jj = t ^ ((row >> 1) & 3);
      const char* src = (const char*)(Ah + (size_t)gr*K + sc*32 + jj*8);
      char* dst = (char*)sA + ((ch & 1)*2 + j)*4096 + wv*1024;
      __builtin_amdgcn_global_load_lds(
          (const __attribute__((address_space(1))) void*)src,
          (__attribute__((address_space(3))) void*)dst, 16, 0, 0);
    }
  };

  f32x4 accH[4][2], accL[4][2];
  #pragma unroll
  for (int mt = 0; mt < 4; ++mt)
    #pragma unroll
    for (int nt = 0; nt < 2; ++nt){
      accH[mt][nt] = (f32x4){0.f,0.f,0.f,0.f};
      accL[mt][nt] = (f32x4){0.f,0.f,0.f,0.f};
    }

  STAGE(0);
  __syncthreads();

  #pragma unroll
  for (int ch = 0; ch < 2; ++ch){
    if (ch == 0) STAGE(1);
    #pragma unroll
    for (int js = 0; js < 2; ++js){
      int sc = ch*2 + js;
      u4h8 bh[2], bl[2];
      #pragma unroll
      for (int nt = 0; nt < 2; ++nt){
        bh[nt].u = *(const uint4*)(bhp[nt] + sc*32);
        bl[nt].u = *(const uint4*)(blp[nt] + sc*32);
      }
      const char* buf = (const char*)sA + ((ch & 1)*2 + js)*4096;
      #pragma unroll
      for (int mt = 0; mt < 4; ++mt){
        int row = mt*16 + ml;
        int ba = row*64 + ((kg ^ ((row >> 1) & 3)) * 16);
        u4h8 A_;
        A_.u = *(const uint4*)(buf + ba);
        #pragma unroll
        for (int nt = 0; nt < 2; ++nt){
          accH[mt][nt] = __builtin_amdgcn_mfma_f32_16x16x32_f16(A_.h, bh[nt].h, accH[mt][nt], 0, 0, 0);
          accL[mt][nt] = __builtin_amdgcn_mfma_f32_16x16x32_f16(A_.h, bl[nt].h, accL[mt][nt], 0, 0, 0);
        }
      }
    }
    __syncthreads();                  // ch0: STAGE(1) done; ch1: sA free before sC overwrite
  }

  #pragma unroll
  for (int mt = 0; mt < 4; ++mt)
    #pragma unroll
    for (int nt = 0; nt < 2; ++nt)
      accH[mt][nt] = accH[mt][nt] + accL[mt][nt] * 9.765625e-4f;

  if constexpr (DOTA || DOTB){
    float vaL[2] = {0.f,0.f}, vbL[2] = {0.f,0.f};
    if constexpr (DOTA){ vaL[0] = va[wv*32 + ml]; vaL[1] = va[wv*32 + 16 + ml]; }
    if constexpr (DOTB){ vbL[0] = vb[wv*32 + ml]; vbL[1] = vb[wv*32 + 16 + ml]; }
    #pragma unroll
    for (int mt = 0; mt < 4; ++mt){
      #pragma unroll
      for (int r = 0; r < 4; ++r){
        float pa = 0.f, pb = 0.f;
        #pragma unroll
        for (int nt = 0; nt < 2; ++nt){
          float v = accH[mt][nt][r];
          if constexpr (DOTA) pa = fmaf(v, vaL[nt], pa);
          if constexpr (DOTB) pb = fmaf(v, vbL[nt], pb);
        }
        #pragma unroll
        for (int o = 8; o; o >>= 1){
          if constexpr (DOTA) pa += __shfl_xor(pa, o, 64);
          if constexpr (DOTB) pb += __shfl_xor(pb, o, 64);
        }
        if (ml == 0){
          int rl = mt*16 + kg*4 + r;
          sd[wv][rl][0] = pa;
          sd[wv][rl][1] = pb;
        }
      }
    }
    __syncthreads();                  // cross-wave sd reduce (keep)
    if (tid < 64){
      int row = R0 + tid;
      if (row < M){
        if constexpr (DOTA)
          outa[row] = sd[0][tid][0] + sd[1][tid][0] + sd[2][tid][0] + sd[3][tid][0];
        if constexpr (DOTB)
          outb[row] = sd[0][tid][1] + sd[1][tid][1] + sd[2][tid][1] + sd[3][tid][1];
      }
    }
  }

  // sC bounce: wave-private region, wave-internal ordering only -> no barriers
  if constexpr (OUTMODE == 2){
    #pragma unroll
    for (int p = 0; p < 2; ++p){
      #pragma unroll
      for (int mh = 0; mh < 2; ++mh){
        int mt = p*2 + mh;
        #pragma unroll
        for (int nt = 0; nt < 2; ++nt){
          #pragma unroll
          for (int r = 0; r < 4; ++r)
            sC[wv][mh*16 + kg*4 + r][nt*16 + ml] = accH[mt][nt][r];
        }
      }
      #pragma unroll
      for (int j = 0; j < 4; ++j){
        int row_l = j*8 + (lane >> 3);
        int c4 = (lane & 7) * 4;
        int grow = R0 + p*32 + row_l;
        if (grow < M){
          float4 v = *(const float4*)&sC[wv][row_l][c4];
          int gcol = wv*32 + c4;
          __half2 h0 = __floats2half2_rn(v.x, v.y);
          __half2 h1 = __floats2half2_rn(v.z, v.w);
          *(uint2*)(Ch + (size_t)grow*128 + gcol) = make_uint2(*(uint32_t*)&h0, *(uint32_t*)&h1);
        }
      }
    }
  }
}

// ============ CSR build (2 edges/thread) ============
__global__ void hist_k(const int* __restrict__ dstv, int* __restrict__ deg, int E){
  int e = (blockIdx.x*256 + threadIdx.x)*2;
  if (e + 1 < E){
    int2 d = *(const int2*)(dstv + e);
    atomicAdd(&deg[d.x], 1);
    atomicAdd(&deg[d.y], 1);
  } else if (e < E){
    atomicAdd(&deg[dstv[e]], 1);
  }
}

// single-pass scan with decoupled lookback (ticket-ordered, all blocks resident)
__global__ void scan_onepass(const int* __restrict__ deg, int* __restrict__ rp,
    int* __restrict__ cur, unsigned long long* __restrict__ bstat,
    int* __restrict__ bctr, int n, int E)
{
  __shared__ int sbid;
  __shared__ int swsum[4];
  __shared__ int sprev;
  if (threadIdx.x == 0) sbid = atomicAdd(bctr, 1);
  __syncthreads();
  const int bid = sbid;
  int i = bid*256 + threadIdx.x;
  int lane = threadIdx.x & 63, wv = threadIdx.x >> 6;
  int v = (i < n) ? deg[i] : 0;
  int inc = v;
  #pragma unroll
  for (int o = 1; o < 64; o <<= 1){
    int u = __shfl_up(inc, o, 64);
    if (lane >= o) inc += u;
  }
  if (lane == 63) swsum[wv] = inc;
  __syncthreads();
  if (threadIdx.x == 0){
    int bsum = swsum[0]+swsum[1]+swsum[2]+swsum[3];
    atomicExch(&bstat[bid], (1ull << 62) | (unsigned long long)(unsigned)bsum);
    int prev = 0;
    for (int j = bid - 1; j >= 0; --j){
      unsigned long long s;
      do { s = atomicAdd(&bstat[j], 0ull); } while ((s >> 62) == 0);
      prev += (int)(s & 0xffffffffull);
      if ((s >> 62) == 2) break;
    }
    atomicExch(&bstat[bid], (2ull << 62) | (unsigned long long)(unsigned)(prev + bsum));
    sprev = prev;
  }
  __syncthreads();
  int woff = sprev;
  for (int wq = 0; wq < wv; ++wq) woff += swsum[wq];
  int excl = woff + inc - v;
  if (i < n){ rp[i] = excl; cur[i] = excl; }
  if (bid == 0 && threadIdx.x == 0) rp[n] = E;
}

__global__ void scatter_k(const int* __restrict__ srcv, const int* __restrict__ dstv,
                          int* __restrict__ cur, int* __restrict__ ssorted, int E){
  int e = (blockIdx.x*256 + threadIdx.x)*2;
  if (e + 1 < E){
    int2 s = *(const int2*)(srcv + e);
    int2 d = *(const int2*)(dstv + e);
    int p0 = atomicAdd(&cur[d.x], 1);
    ssorted[p0] = s.x;
    int p1 = atomicAdd(&cur[d.y], 1);
    ssorted[p1] = s.y;
  } else if (e < E){
    int p = atomicAdd(&cur[dstv[e]], 1);
    ssorted[p] = srcv[e];
  }
}

// ============ fused segment softmax + aggregation: 16-lane group per dst node ============
// 4 dst/wave. Lane covers 8 features (uint4 = 16B loads). Inner loop: unconditional
// 4-wide batches (ghost lanes have alpha==0, sid==0) -> 4 gathers in flight.
__global__ __launch_bounds__(256) void gat_agg(const int* __restrict__ ssorted,
    const int* __restrict__ rp,
    const float* __restrict__ asn, const float* __restrict__ adn,
    const uint4* __restrict__ hsv, const float* __restrict__ bias,
    uint4* __restrict__ outv, int Nn)
{
  const int lane = threadIdx.x & 63;
  const int wv = threadIdx.x >> 6;
  const int l16 = lane & 15;
  const int gbase = lane & 48;
  const int d = blockIdx.x*16 + wv*4 + (lane >> 4);
  const bool valid = d < Nn;
  const int dc = valid ? d : Nn-1;
  const int lo = rp[dc], hi = rp[dc+1];
  const int deg = valid ? (hi - lo) : 0;
  const float ad = adn[dc];
  float acc[8] = {0.f,0.f,0.f,0.f,0.f,0.f,0.f,0.f};

  const bool fast = (deg <= 16);
  const int fdeg = fast ? deg : 0;
  int mdeg = fdeg;
  mdeg = max(mdeg, __shfl_xor(mdeg, 16, 64));
  mdeg = max(mdeg, __shfl_xor(mdeg, 32, 64));
  const int nb = (mdeg + 3) & ~3;          // wave-uniform, <= 16

  int sid = 0; float lg = -1e30f;
  if (l16 < fdeg){
    sid = ssorted[lo + l16];
    lg = lrelu(asn[sid] + ad);
  }
  float m = lg;
  m = fmaxf(m, __shfl_xor(m, 8, 64));
  m = fmaxf(m, __shfl_xor(m, 4, 64));
  m = fmaxf(m, __shfl_xor(m, 2, 64));
  m = fmaxf(m, __shfl_xor(m, 1, 64));
  float p = (l16 < fdeg) ? __expf(lg - m) : 0.f;
  float s = p;
  s += __shfl_xor(s, 8, 64);
  s += __shfl_xor(s, 4, 64);
  s += __shfl_xor(s, 2, 64);
  s += __shfl_xor(s, 1, 64);
  float alpha = p * (1.f / (s + 1e-16f));

  for (int i = 0; i < nb; i += 4){
    float al[4]; int sd[4]; uint4 v[4];
    #pragma unroll
    for (int j = 0; j < 4; ++j){
      al[j] = __shfl(alpha, gbase + i + j, 64);
      sd[j] = __shfl(sid, gbase + i + j, 64);
    }
    #pragma unroll
    for (int j = 0; j < 4; ++j)
      v[j] = hsv[(size_t)sd[j]*16 + l16];
    #pragma unroll
    for (int j = 0; j < 4; ++j){
      float2 f0 = __half22float2(*(__half2*)&v[j].x);
      float2 f1 = __half22float2(*(__half2*)&v[j].y);
      float2 f2 = __half22float2(*(__half2*)&v[j].z);
      float2 f3 = __half22float2(*(__half2*)&v[j].w);
      acc[0] = fmaf(al[j], f0.x, acc[0]); acc[1] = fmaf(al[j], f0.y, acc[1]);
      acc[2] = fmaf(al[j], f1.x, acc[2]); acc[3] = fmaf(al[j], f1.y, acc[3]);
      acc[4] = fmaf(al[j], f2.x, acc[4]); acc[5] = fmaf(al[j], f2.y, acc[5]);
      acc[6] = fmaf(al[j], f3.x, acc[6]); acc[7] = fmaf(al[j], f3.y, acc[7]);
    }
  }

  if (!fast){                                // rare: deg > 16
    float mg = -1e30f;
    for (int e = l16; e < deg; e += 16){
      int sd = ssorted[lo + e];
      mg = fmaxf(mg, lrelu(asn[sd] + ad));
    }
    mg = fmaxf(mg, __shfl_xor(mg, 8, 64));
    mg = fmaxf(mg, __shfl_xor(mg, 4, 64));
    mg = fmaxf(mg, __shfl_xor(mg, 2, 64));
    mg = fmaxf(mg, __shfl_xor(mg, 1, 64));
    float sg = 0.f;
    for (int e = l16; e < deg; e += 16){
      int sd = ssorted[lo + e];
      sg += __expf(lrelu(asn[sd] + ad) - mg);
    }
    sg += __shfl_xor(sg, 8, 64);
    sg += __shfl_xor(sg, 4, 64);
    sg += __shfl_xor(sg, 2, 64);
    sg += __shfl_xor(sg, 1, 64);
    float inv = 1.f / (sg + 1e-16f);
    for (int e = 0; e < deg; ++e){
      int sd = ssorted[lo + e];
      float a = __expf(lrelu(asn[sd] + ad) - mg) * inv;
      uint4 v = hsv[(size_t)sd*16 + l16];
      float2 f0 = __half22float2(*(__half2*)&v.x);
      float2 f1 = __half22float2(*(__half2*)&v.y);
      float2 f2 = __half22float2(*(__half2*)&v.z);
      float2 f3 = __half22float2(*(__half2*)&v.w);
      acc[0] = fmaf(a, f0.x, acc[0]); acc[1] = fmaf(a, f0.y, acc[1]);
      acc[2] = fmaf(a, f1.x, acc[2]); acc[3] = fmaf(a, f1.y, acc[3]);
      acc[4] = fmaf(a, f2.x, acc[4]); acc[5] = fmaf(a, f2.y, acc[5]);
      acc[6] = fmaf(a, f3.x, acc[6]); acc[7] = fmaf(a, f3.y, acc[7]);
    }
  }

  if (valid){
    float4 b0 = ((const float4*)bias)[l16*2];
    float4 b1 = ((const float4*)bias)[l16*2 + 1];
    __half2 h0 = __floats2half2_rn(elu1(acc[0]+b0.x), elu1(acc[1]+b0.y));
    __half2 h1 = __floats2half2_rn(elu1(acc[2]+b0.z), elu1(acc[3]+b0.w));
    __half2 h2 = __floats2half2_rn(elu1(acc[4]+b1.x), elu1(acc[5]+b1.y));
    __half2 h3 = __floats2half2_rn(elu1(acc[6]+b1.z), elu1(acc[7]+b1.w));
    outv[(size_t)d*16 + l16] = make_uint4(*(uint32_t*)&h0, *(uint32_t*)&h1,
                                          *(uint32_t*)&h2, *(uint32_t*)&h3);
  }
}

// ============ graph pooling: 16-lane group per graph ============
__global__ __launch_bounds__(256) void pool_relu(const uint4* __restrict__ hv,
    const int* __restrict__ batch, uint4* __restrict__ ptail, int Nn, int G)
{
  const int lane = threadIdx.x & 63;
  const int wv = threadIdx.x >> 6;
  const int l16 = lane & 15;
  const int g = blockIdx.x*16 + wv*4 + (lane >> 4);
  if (g >= G) return;
  const int lo = lower_bound_i(batch, Nn, g);
  const int hi = lower_bound_i(batch, Nn, g + 1);
  float acc[8] = {0.f,0.f,0.f,0.f,0.f,0.f,0.f,0.f};
  for (int i = lo; i < hi; ++i){
    uint4 v = hv[(size_t)i*16 + l16];
    float2 f0 = __half22float2(*(__half2*)&v.x);
    float2 f1 = __half22float2(*(__half2*)&v.y);
    float2 f2 = __half22float2(*(__half2*)&v.z);
    float2 f3 = __half22float2(*(__half2*)&v.w);
    acc[0] += f0.x; acc[1] += f0.y; acc[2] += f1.x; acc[3] += f1.y;
    acc[4] += f2.x; acc[5] += f2.y; acc[6] += f3.x; acc[7] += f3.y;
  }
  __half2 h0 = __floats2half2_rn(fmaxf(acc[0],0.f), fmaxf(acc[1],0.f));
  __half2 h1 = __floats2half2_rn(fmaxf(acc[2],0.f), fmaxf(acc[3],0.f));
  __half2 h2 = __floats2half2_rn(fmaxf(acc[4],0.f), fmaxf(acc[5],0.f));
  __half2 h3 = __floats2half2_rn(fmaxf(acc[6],0.f), fmaxf(acc[7],0.f));
  ptail[(size_t)g*16 + l16] = make_uint4(*(uint32_t*)&h0, *(uint32_t*)&h1,
                                         *(uint32_t*)&h2, *(uint32_t*)&h3);
}

// ============ molecular GAT aggregate + final linear (fused) ============
__global__ __launch_bounds__(128) void mol_agg(const float* __restrict__ as2,
    const float* __restrict__ ad2, const unsigned short* __restrict__ hs2,
    const int* __restrict__ batch, const float* __restrict__ bias,
    const float* __restrict__ W2, const float* __restrict__ b2,
    float* __restrict__ out, int Nn)
{
  const int g = blockIdx.x;
  const int c = threadIdx.x;
  __shared__ int sb[2];
  __shared__ float red[2];
  if (c < 2) sb[c] = lower_bound_i(batch, Nn, g + c);
  __syncthreads();
  const int lo = sb[0], hi = sb[1];
  const float ad = ad2[g];

  float mt = -1e30f;
  for (int i = lo + c; i < hi; i += 128) mt = fmaxf(mt, lrelu(as2[i] + ad));
  #pragma unroll
  for (int o = 32; o; o >>= 1) mt = fmaxf(mt, __shfl_xor(mt, o, 64));
  if ((c & 63) == 0) red[c >> 6] = mt;
  __syncthreads();
  const float m = fmaxf(red[0], red[1]);

  float st = 0.f;
  for (int i = lo + c; i < hi; i += 128) st += __expf(lrelu(as2[i] + ad) - m);
  #pragma unroll
  for (int o = 32; o; o >>= 1) st += __shfl_xor(st, o, 64);
  __syncthreads();
  if ((c & 63) == 0) red[c >> 6] = st;
  __syncthreads();
  const float inv = 1.f / (red[0] + red[1] + 1e-16f);

  float acc = 0.f;
  for (int i = lo; i < hi; ++i){
    float wgt = __expf(lrelu(as2[i] + ad) - m) * inv;
    acc = fmaf(wgt, __half2float(__ushort_as_half(hs2[(size_t)i*128 + c])), acc);
  }
  float v = elu1(acc + bias[c]);

  float r = v * W2[c];
  #pragma unroll
  for (int o = 32; o; o >>= 1) r += __shfl_xor(r, o, 64);
  __syncthreads();
  if ((c & 63) == 0) red[c >> 6] = r;
  __syncthreads();
  if (c == 0) out[g] = red[0] + red[1] + b2[0];
}

extern "C" void kernel_launch(void* const* d_in, const int* in_sizes, int n_in,
                              void* d_out, int out_size, void* d_ws, size_t ws_size,
                              hipStream_t stream)
{
  const float* x      = (const float*)d_in[0];
  const int*   ei     = (const int*)  d_in[1];
  const int*   batch  = (const int*)  d_in[2];
  const float* W1     = (const float*)d_in[3];
  const float* b1     = (const float*)d_in[4];
  const float* gW     = (const float*)d_in[5];
  const float* g_asrc = (const float*)d_in[6];
  const float* g_adst = (const float*)d_in[7];
  const float* g_b    = (const float*)d_in[8];
  const float* mW     = (const float*)d_in[9];
  const float* m_asrc = (const float*)d_in[10];
  const float* m_adst = (const float*)d_in[11];
  const float* m_b    = (const float*)d_in[12];
  const float* W2     = (const float*)d_in[13];
  const float* b2     = (const float*)d_in[14];

  const int Nn = in_sizes[0] / 64;            // 100000
  const int E  = in_sizes[1] / 2;             // 400000
  const int G  = out_size;                    // 5000
  const int NL = in_sizes[5] / (128*128);     // 3
  const int M2 = Nn + G;
  const int* srcv = ei;
  const int* dstv = ei + E;

  char* w = (char*)d_ws;
  unsigned short* h16 = (unsigned short*)w; w += (size_t)(M2+64)*128*2;
  unsigned short* hsR = (unsigned short*)w; w += (size_t)(M2+64)*128*2;
  float* asO      = (float*)w; w += (size_t)(M2+64)*4;
  float* adO      = (float*)w; w += (size_t)(M2+64)*4;
  int*   deg      = (int*)w;   w += (size_t)Nn*4;
  int*   rp       = (int*)w;   w += (size_t)(Nn+64)*4;
  int*   cur      = (int*)w;   w += (size_t)Nn*4;
  int*   ssorted  = (int*)w;   w += (size_t)E*4;
  unsigned long long* bstat = (unsigned long long*)w; w += 512*8;
  int*   bctr     = (int*)w;   w += 64;
  unsigned short* w1h = (unsigned short*)w; w += 64*128*2;
  unsigned short* w1l = (unsigned short*)w; w += 64*128*2;
  unsigned short* gwh = (unsigned short*)w; w += (size_t)NL*128*128*2;
  unsigned short* gwl = (unsigned short*)w; w += (size_t)NL*128*128*2;
  unsigned short* mwh = (unsigned short*)w; w += 128*128*2;
  unsigned short* mwl = (unsigned short*)w; w += 128*128*2;

  const int nscan = (Nn + 255)/256;
  const int nrt = (Nn + 63)/64;
  const int mrt = (M2 + 63)/64;
  const int ne2 = (E/2 + 255)/256;

  // ---- prep (weights + zero CSR/scan state) ----
  wprep_all<<<nscan, 256, 0, stream>>>(W1, gW, mW, w1h, w1l, gwh, gwl, mwh, mwl,
                                       deg, bstat, bctr, Nn, NL*16384, nscan);

  // ---- CSR build ----
  hist_k<<<ne2, 256, 0, stream>>>(dstv, deg, E);
  scan_onepass<<<nscan, 256, 0, stream>>>(deg, rp, cur, bstat, bctr, Nn, E);
  scatter_k<<<ne2, 256, 0, stream>>>(srcv, dstv, cur, ssorted, E);

  // ---- lin1 ----
  gemm_lin1<<<nrt, 256, 0, stream>>>(x, w1h, w1l, b1, h16, Nn);

  // ---- 3 GAT layers ----
  for (int l = 0; l < NL; ++l){
    gemm_mfma<2, true, true><<<nrt, 256, 0, stream>>>(
        h16, gwh + (size_t)l*128*128, gwl + (size_t)l*128*128,
        g_asrc + l*128, g_adst + l*128, hsR, asO, adO, Nn);
    gat_agg<<<(Nn+15)/16, 256, 0, stream>>>(ssorted, rp, asO, adO,
        (const uint4*)hsR, g_b + l*128, (uint4*)h16, Nn);
  }

  // ---- readout ----
  pool_relu<<<(G+15)/16, 256, 0, stream>>>((const uint4*)h16, batch,
      (uint4*)(h16 + (size_t)Nn*128), Nn, G);
  gemm_mfma<2, true, true><<<mrt, 256, 0, stream>>>(
      h16, mwh, mwl, m_asrc, m_adst, hsR, asO, adO, M2);
  mol_agg<<<G, 128, 0, stream>>>(asO, adO + Nn, hsR, batch, m_b, W2, b2, (float*)d_out, Nn);
}